// Round 5
// baseline (154.453 us; speedup 1.0000x reference)
//
#include <hip/hip_runtime.h>
#include <hip/hip_bf16.h>

#define OUT_N 8192
#define IN_K  8192
#define M_ROWS 64

typedef __attribute__((ext_vector_type(8))) short  bf16x8;
typedef __attribute__((ext_vector_type(4))) float  f32x4;
typedef __attribute__((ext_vector_type(4))) int    int4v;

__device__ const float NF4_TAB[16] = {
  -1.0f, -0.6961928009986877f, -0.5250730514526367f, -0.39491748809814453f,
  -0.28444138169288635f, -0.18477343022823334f, -0.09105003625154495f, 0.0f,
  0.07958029955625534f, 0.16093020141124725f, 0.24611230850219726f,
  0.33791524171829224f, 0.44070982933044434f, 0.5626170039176941f,
  0.7229568362236023f, 1.0f };

static __device__ __forceinline__ unsigned short f2bf(float f) {
  union { __hip_bfloat16 h; unsigned short s; } u;
  u.h = __float2bfloat16(f);
  return u.s;
}

// Repack x (fp32 [64][8192]) -> bf16 MFMA A-fragment order.
// xf[((ks*4 + mt)*64 + lane)*8 + j] = bf16(x[mt*16+(lane&15)][ks*32+(lane>>4)*8+j])
__global__ __launch_bounds__(256) void qlin_prep(const float* __restrict__ x,
                                                 unsigned short* __restrict__ xf) {
  int t = blockIdx.x * 256 + threadIdx.x;          // (ks, mt, lane)
  int lane = t & 63, mt = (t >> 6) & 3, ks = t >> 8;
  int ri = lane & 15, kbb = lane >> 4;
  const float* src = x + (size_t)(mt * 16 + ri) * IN_K + ks * 32 + kbb * 8;
  f32x4 a = *(const f32x4*)src;
  f32x4 c = *(const f32x4*)(src + 4);
  bf16x8 o;
  o[0] = (short)f2bf(a[0]); o[1] = (short)f2bf(a[1]);
  o[2] = (short)f2bf(a[2]); o[3] = (short)f2bf(a[3]);
  o[4] = (short)f2bf(c[0]); o[5] = (short)f2bf(c[1]);
  o[6] = (short)f2bf(c[2]); o[7] = (short)f2bf(c[3]);
  ((bf16x8*)xf)[t] = o;
}

// Fused NF4 dequant + GEMM.
// KEY: pk loads are COALESCED (lane l -> col l>>2, kb l&3, 4-lane clusters read
// contiguous 64B), then redistributed in-register via 4x ds_bpermute per k-step.
// pk ring depth 8 (regs), A depth 2 (L2-resident xf), no barriers in the loop.
template<int NC>
__global__ __launch_bounds__(256, 4) void qlin_main(
    const int*   __restrict__ packed,
    const float* __restrict__ absmax,
    const unsigned short* __restrict__ xf,
    float*       __restrict__ parts) {
  constexpr int KCn = IN_K / NC;      // k per chunk
  constexpr int NIT = KCn / 32;       // k-steps per chunk
  constexpr int LOG = (NC == 8) ? 3 : 2;

  __shared__ unsigned int lut[256];   // byte -> {bf16(nf4[lo]), bf16(nf4[hi])}
  {
    int t = threadIdx.x;
    unsigned lo = f2bf(NF4_TAB[t & 15]);
    unsigned hi = f2bf(NF4_TAB[(t >> 4) & 15]);
    lut[t] = lo | (hi << 16);
  }
  __syncthreads();

  const int l     = threadIdx.x & 63;
  const int w     = threadIdx.x >> 6;
  const int ntile = (int)blockIdx.x >> LOG;
  const int chunk = (int)blockIdx.x & (NC - 1);
  const int colg0 = ntile * 64 + w * 16;          // wave's first col
  const int col   = colg0 + (l & 15);             // this lane's MFMA col
  const int kb    = l >> 4;                       // MFMA k-quarter
  const int kc0   = chunk * KCn;
  const int ksg0  = kc0 >> 5;

  // coalesced pk addressing: lane l covers (src_col = colg0 + (l>>2), src_kb = l&3)
  const int* pcoal = packed + ((size_t)(colg0 + (l >> 2)) * (IN_K / 2))
                   + (kc0 / 2) + (l & 3) * 4;
  // bpermute index: dest lane (c = l&15, q = l>>4) pulls from src lane c*4 + q
  const int bpidx = (((l & 15) << 2) | (l >> 4)) << 2;

  const char* xbase = (const char*)xf + (size_t)ksg0 * 4096 + l * 16;
  const f32x4* aptr4 = (const f32x4*)(absmax + (size_t)col * 128 + (kc0 >> 6));

  // ---- prologue: A depth 2 first (so A-waits never force young pk loads), pk ring 8
  bf16x8 Acur[4], Anx[4];
  #pragma unroll
  for (int mt = 0; mt < 4; ++mt) Acur[mt] = *(const bf16x8*)(xbase + mt * 1024);
  #pragma unroll
  for (int mt = 0; mt < 4; ++mt) Anx[mt] = *(const bf16x8*)(xbase + 4096 + mt * 1024);
  int4v pk[8];
  #pragma unroll
  for (int i = 0; i < 8; ++i) pk[i] = *(const int4v*)(pcoal + i * 16);

  f32x4 amx = aptr4[0], amxn = amx;
  const f32x4 zro = {0.f, 0.f, 0.f, 0.f};
  f32x4 mn[4] = {zro, zro, zro, zro};
  f32x4 sb[4];

  #pragma unroll
  for (int u = 0; u < NIT; ++u) {
    // ---- load cluster: A(u+2) then pk(u+8) (clamped; uniform counts every iter)
    const int ak = (u + 2 < NIT) ? u + 2 : NIT - 1;
    const int sk = (u + 8 < NIT) ? u + 8 : NIT - 1;
    bf16x8 nA0 = *(const bf16x8*)(xbase + (size_t)ak * 4096 + 0 * 1024);
    bf16x8 nA1 = *(const bf16x8*)(xbase + (size_t)ak * 4096 + 1 * 1024);
    bf16x8 nA2 = *(const bf16x8*)(xbase + (size_t)ak * 4096 + 2 * 1024);
    bf16x8 nA3 = *(const bf16x8*)(xbase + (size_t)ak * 4096 + 3 * 1024);
    int4v npk = *(const int4v*)(pcoal + (size_t)sk * 16);
    if ((u & 7) == 0) {
      int aq = (u >> 3) + 1;
      if (aq > NIT / 8 - 1) aq = NIT / 8 - 1;
      amxn = aptr4[aq];
    }
    __builtin_amdgcn_sched_barrier(0);   // pin: loads issue before this iter's compute

    // ---- redistribute coalesced pk to MFMA lane layout (4 dword bpermutes)
    int4v raw = pk[u & 7];
    int4v cur;
    #pragma unroll
    for (int i = 0; i < 4; ++i)
      cur[i] = __builtin_amdgcn_ds_bpermute(bpidx, raw[i]);

    // ---- dequant: 4 pair-LUT reads, zero arithmetic
    int4v bw;
    #pragma unroll
    for (int i = 0; i < 4; ++i) bw[i] = (int)lut[cur[i] & 255];
    union { int4v i; bf16x8 h; } cvt; cvt.i = bw;
    const bf16x8 b = cvt.h;

    // ---- MFMA into 64-k group sub-acc; fold absmax on group close
    if ((u & 1) == 0) {
      #pragma unroll
      for (int mt = 0; mt < 4; ++mt)
        sb[mt] = __builtin_amdgcn_mfma_f32_16x16x32_bf16(Acur[mt], b, zro, 0, 0, 0);
    } else {
      #pragma unroll
      for (int mt = 0; mt < 4; ++mt)
        sb[mt] = __builtin_amdgcn_mfma_f32_16x16x32_bf16(Acur[mt], b, sb[mt], 0, 0, 0);
      const float am = amx[(u >> 1) & 3];
      #pragma unroll
      for (int mt = 0; mt < 4; ++mt)
        mn[mt] += sb[mt] * am;
    }

    // ---- rotate pipeline registers (static indices; SSA-coalesced)
    #pragma unroll
    for (int mt = 0; mt < 4; ++mt) { Acur[mt] = Anx[mt]; }
    Anx[0] = nA0; Anx[1] = nA1; Anx[2] = nA2; Anx[3] = nA3;
    pk[u & 7] = npk;
    if ((u & 7) == 7) amx = amxn;
  }

  // epilogue: D mapping col=lane&15, row=(lane>>4)*4+reg; fp32 dword stores
  float* po = parts + (size_t)chunk * M_ROWS * OUT_N + col;
  const int rbase = kb * 4;
  #pragma unroll
  for (int mt = 0; mt < 4; ++mt) {
    #pragma unroll
    for (int r = 0; r < 4; ++r)
      po[(size_t)(mt * 16 + rbase + r) * OUT_N] = mn[mt][r];
  }
}

template<int NC>
__global__ __launch_bounds__(256) void qlin_reduce(
    const float* __restrict__ parts,
    const float* __restrict__ bias,
    float*       __restrict__ out) {
  const int TOT4 = M_ROWS * OUT_N / 4;   // 131072
  int i4 = blockIdx.x * 256 + threadIdx.x;
  if (i4 >= TOT4) return;
  const f32x4* p = (const f32x4*)parts;
  f32x4 s = p[i4];
  #pragma unroll
  for (int c = 1; c < NC; ++c) s += p[i4 + c * TOT4];
  f32x4 bb = ((const f32x4*)bias)[i4 & (OUT_N / 4 - 1)];
  ((f32x4*)out)[i4] = s + bb;
}

extern "C" void kernel_launch(void* const* d_in, const int* in_sizes, int n_in,
                              void* d_out, int out_size, void* d_ws, size_t ws_size,
                              hipStream_t stream) {
  const float* x      = (const float*)d_in[0];
  const int*   packed = (const int*)d_in[1];
  const float* absmax = (const float*)d_in[2];
  const float* bias   = (const float*)d_in[3];
  float* out = (float*)d_out;

  unsigned short* xf = (unsigned short*)d_ws;                  // 1 MB
  float* parts = (float*)((char*)d_ws + (1 << 20));            // NC * 2 MB fp32

  qlin_prep<<<(M_ROWS * IN_K / 8 + 255) / 256, 256, 0, stream>>>(x, xf);

  const size_t need8 = (size_t)(1 << 20)
                     + (size_t)8 * M_ROWS * OUT_N * sizeof(float);
  if (ws_size >= need8) {
    qlin_main<8><<<(OUT_N / 64) * 8, 256, 0, stream>>>(packed, absmax, xf, parts);
    qlin_reduce<8><<<(M_ROWS * OUT_N / 4 + 255) / 256, 256, 0, stream>>>(parts, bias, out);
  } else {
    qlin_main<4><<<(OUT_N / 64) * 4, 256, 0, stream>>>(packed, absmax, xf, parts);
    qlin_reduce<4><<<(M_ROWS * OUT_N / 4 + 255) / 256, 256, 0, stream>>>(parts, bias, out);
  }
}

// Round 6
// 49.037 us; speedup vs baseline: 3.1497x; 3.1497x over previous
//
#include <hip/hip_runtime.h>
#include <hip/hip_bf16.h>

#define OUT_N 8192
#define IN_K  8192
#define M_ROWS 64

typedef __attribute__((ext_vector_type(8))) short  bf16x8;
typedef __attribute__((ext_vector_type(4))) float  f32x4;
typedef __attribute__((ext_vector_type(4))) int    int4v;

__device__ const float NF4_TAB[16] = {
  -1.0f, -0.6961928009986877f, -0.5250730514526367f, -0.39491748809814453f,
  -0.28444138169288635f, -0.18477343022823334f, -0.09105003625154495f, 0.0f,
  0.07958029955625534f, 0.16093020141124725f, 0.24611230850219726f,
  0.33791524171829224f, 0.44070982933044434f, 0.5626170039176941f,
  0.7229568362236023f, 1.0f };

static __device__ __forceinline__ unsigned short f2bf(float f) {
  union { __hip_bfloat16 h; unsigned short s; } u;
  u.h = __float2bfloat16(f);
  return u.s;
}

// Repack x (fp32 [64][8192]) -> bf16 MFMA A-fragment order.
// xf[((ks*4 + mt)*64 + lane)*8 + j] = bf16(x[mt*16+(lane&15)][ks*32+(lane>>4)*8+j])
__global__ __launch_bounds__(256) void qlin_prep(const float* __restrict__ x,
                                                 unsigned short* __restrict__ xf) {
  int t = blockIdx.x * 256 + threadIdx.x;          // (ks, mt, lane)
  int lane = t & 63, mt = (t >> 6) & 3, ks = t >> 8;
  int ri = lane & 15, kbb = lane >> 4;
  const float* src = x + (size_t)(mt * 16 + ri) * IN_K + ks * 32 + kbb * 8;
  f32x4 a = *(const f32x4*)src;
  f32x4 c = *(const f32x4*)(src + 4);
  bf16x8 o;
  o[0] = (short)f2bf(a[0]); o[1] = (short)f2bf(a[1]);
  o[2] = (short)f2bf(a[2]); o[3] = (short)f2bf(a[3]);
  o[4] = (short)f2bf(c[0]); o[5] = (short)f2bf(c[1]);
  o[6] = (short)f2bf(c[2]); o[7] = (short)f2bf(c[3]);
  ((bf16x8*)xf)[t] = o;
}

static __device__ __forceinline__ bf16x8 deq(const unsigned int* lut, int4v cur) {
  int4v bw;
  bw[0] = (int)lut[cur[0] & 255];
  bw[1] = (int)lut[cur[1] & 255];
  bw[2] = (int)lut[cur[2] & 255];
  bw[3] = (int)lut[cur[3] & 255];
  union { int4v i; bf16x8 h; } c; c.i = bw;
  return c.h;
}

// load one k-step's 4 A-fragments (xbase pre-offset by l*16)
#define LOADA(D0, D1, D2, D3, ks) {                                          \
    const char* _p = xbase + (size_t)(ks) * 4096;                            \
    D0 = *(const bf16x8*)(_p);                                               \
    D1 = *(const bf16x8*)(_p + 1024);                                        \
    D2 = *(const bf16x8*)(_p + 2048);                                        \
    D3 = *(const bf16x8*)(_p + 3072); }

// one k-step: loads first (A 2-ahead into same parity buffer, pk 4-ahead ring),
// then dequant + 4 MFMA. EVEN opens a 64k-group (C=0), ODD closes (fold amax).
#define QSTEP_EVEN(U4, PKV, B0, B1, B2, B3) {                                \
    int aks = KS + (U4) + 2; if (aks > NITm1) aks = NITm1;                   \
    int pks = KS + (U4) + 4; if (pks > NITm1) pks = NITm1;                   \
    bf16x8 n0, n1, n2, n3;                                                   \
    LOADA(n0, n1, n2, n3, aks);                                              \
    int4v npk = *(const int4v*)(pbase + (size_t)pks * 64);                   \
    bf16x8 b = deq(lut, PKV);                                                \
    sb0 = __builtin_amdgcn_mfma_f32_16x16x32_bf16(B0, b, zro, 0, 0, 0);      \
    sb1 = __builtin_amdgcn_mfma_f32_16x16x32_bf16(B1, b, zro, 0, 0, 0);      \
    sb2 = __builtin_amdgcn_mfma_f32_16x16x32_bf16(B2, b, zro, 0, 0, 0);      \
    sb3 = __builtin_amdgcn_mfma_f32_16x16x32_bf16(B3, b, zro, 0, 0, 0);      \
    B0 = n0; B1 = n1; B2 = n2; B3 = n3; PKV = npk; }

#define QSTEP_ODD(U4, PKV, B0, B1, B2, B3, AM) {                             \
    int aks = KS + (U4) + 2; if (aks > NITm1) aks = NITm1;                   \
    int pks = KS + (U4) + 4; if (pks > NITm1) pks = NITm1;                   \
    bf16x8 n0, n1, n2, n3;                                                   \
    LOADA(n0, n1, n2, n3, aks);                                              \
    int4v npk = *(const int4v*)(pbase + (size_t)pks * 64);                   \
    bf16x8 b = deq(lut, PKV);                                                \
    sb0 = __builtin_amdgcn_mfma_f32_16x16x32_bf16(B0, b, sb0, 0, 0, 0);      \
    sb1 = __builtin_amdgcn_mfma_f32_16x16x32_bf16(B1, b, sb1, 0, 0, 0);      \
    sb2 = __builtin_amdgcn_mfma_f32_16x16x32_bf16(B2, b, sb2, 0, 0, 0);      \
    sb3 = __builtin_amdgcn_mfma_f32_16x16x32_bf16(B3, b, sb3, 0, 0, 0);      \
    mn0 += sb0 * (AM); mn1 += sb1 * (AM);                                    \
    mn2 += sb2 * (AM); mn3 += sb3 * (AM);                                    \
    B0 = n0; B1 = n1; B2 = n2; B3 = n3; PKV = npk; }

// Fused NF4 dequant + GEMM. All pipeline state in NAMED registers (no arrays,
// no dynamic indices -> structurally impossible to spill to scratch rings).
// No barriers after the LUT fill. A: double-buffered per parity, 2-ahead from
// L2-resident xf. pk: 4-deep named ring from packed (L3-resident on replay).
template<int NC>
__global__ __launch_bounds__(256, 4) void qlin_main(
    const int*   __restrict__ packed,
    const float* __restrict__ absmax,
    const unsigned short* __restrict__ xf,
    float*       __restrict__ parts) {
  constexpr int KCn   = IN_K / NC;     // k per chunk
  constexpr int NIT   = KCn / 32;      // k-steps per chunk (32 for NC=8)
  constexpr int NITm1 = NIT - 1;
  constexpr int NGRP  = NIT / 4;
  constexpr int LOG   = (NC == 8) ? 3 : 2;

  __shared__ unsigned int lut[256];    // byte -> {bf16(nf4[lo]), bf16(nf4[hi])}
  {
    int t = threadIdx.x;
    unsigned lo = f2bf(NF4_TAB[t & 15]);
    unsigned hi = f2bf(NF4_TAB[(t >> 4) & 15]);
    lut[t] = lo | (hi << 16);
  }
  __syncthreads();

  const int l     = threadIdx.x & 63;
  const int w     = threadIdx.x >> 6;
  const int ntile = (int)blockIdx.x >> LOG;
  const int chunk = (int)blockIdx.x & (NC - 1);   // == XCD id -> chunk-per-XCD L2 locality
  const int col   = ntile * 64 + w * 16 + (l & 15);
  const int kb    = l >> 4;
  const int kc0   = chunk * KCn;
  const int ksg0  = kc0 >> 5;

  const char* pbase = (const char*)packed
                    + ((size_t)col * (IN_K / 2) + kc0 / 2) * 4 + kb * 16;
  const char* xbase = (const char*)xf + (size_t)ksg0 * 4096 + l * 16;
  const float* aptr = absmax + (size_t)col * 128 + (kc0 >> 6);
  constexpr int AMX = NIT / 2 - 1;

  const f32x4 zro = {0.f, 0.f, 0.f, 0.f};
  f32x4 mn0 = zro, mn1 = zro, mn2 = zro, mn3 = zro;
  f32x4 sb0, sb1, sb2, sb3;
  bf16x8 Ae0, Ae1, Ae2, Ae3, Ao0, Ao1, Ao2, Ao3;
  int4v pk0, pk1, pk2, pk3;

  // prologue
  LOADA(Ae0, Ae1, Ae2, Ae3, 0);
  LOADA(Ao0, Ao1, Ao2, Ao3, 1);
  pk0 = *(const int4v*)(pbase);
  pk1 = *(const int4v*)(pbase + 64);
  pk2 = *(const int4v*)(pbase + 128);
  pk3 = *(const int4v*)(pbase + 192);
  float amE = aptr[0], amO = aptr[1];

  for (int g = 0; g < NGRP; ++g) {
    const int KS = g * 4;
    int ia = 2 * g + 2; if (ia > AMX) ia = AMX;
    int ib = 2 * g + 3; if (ib > AMX) ib = AMX;
    float pmE = aptr[ia], pmO = aptr[ib];

    QSTEP_EVEN(0, pk0, Ae0, Ae1, Ae2, Ae3)
    QSTEP_ODD (1, pk1, Ao0, Ao1, Ao2, Ao3, amE)
    QSTEP_EVEN(2, pk2, Ae0, Ae1, Ae2, Ae3)
    QSTEP_ODD (3, pk3, Ao0, Ao1, Ao2, Ao3, amO)

    amE = pmE; amO = pmO;
  }

  // epilogue: D mapping col=lane&15, row=(lane>>4)*4+reg; fp32 dword stores
  float* po = parts + (size_t)chunk * M_ROWS * OUT_N + col;
  const int rbase = kb * 4;
  po[(size_t)(0  + rbase + 0) * OUT_N] = mn0[0];
  po[(size_t)(0  + rbase + 1) * OUT_N] = mn0[1];
  po[(size_t)(0  + rbase + 2) * OUT_N] = mn0[2];
  po[(size_t)(0  + rbase + 3) * OUT_N] = mn0[3];
  po[(size_t)(16 + rbase + 0) * OUT_N] = mn1[0];
  po[(size_t)(16 + rbase + 1) * OUT_N] = mn1[1];
  po[(size_t)(16 + rbase + 2) * OUT_N] = mn1[2];
  po[(size_t)(16 + rbase + 3) * OUT_N] = mn1[3];
  po[(size_t)(32 + rbase + 0) * OUT_N] = mn2[0];
  po[(size_t)(32 + rbase + 1) * OUT_N] = mn2[1];
  po[(size_t)(32 + rbase + 2) * OUT_N] = mn2[2];
  po[(size_t)(32 + rbase + 3) * OUT_N] = mn2[3];
  po[(size_t)(48 + rbase + 0) * OUT_N] = mn3[0];
  po[(size_t)(48 + rbase + 1) * OUT_N] = mn3[1];
  po[(size_t)(48 + rbase + 2) * OUT_N] = mn3[2];
  po[(size_t)(48 + rbase + 3) * OUT_N] = mn3[3];
}

template<int NC>
__global__ __launch_bounds__(256) void qlin_reduce(
    const float* __restrict__ parts,
    const float* __restrict__ bias,
    float*       __restrict__ out) {
  const int TOT4 = M_ROWS * OUT_N / 4;   // 131072
  int i4 = blockIdx.x * 256 + threadIdx.x;
  if (i4 >= TOT4) return;
  const f32x4* p = (const f32x4*)parts;
  f32x4 s = p[i4];
  #pragma unroll
  for (int c = 1; c < NC; ++c) s += p[i4 + c * TOT4];
  f32x4 bb = ((const f32x4*)bias)[i4 & (OUT_N / 4 - 1)];
  ((f32x4*)out)[i4] = s + bb;
}

extern "C" void kernel_launch(void* const* d_in, const int* in_sizes, int n_in,
                              void* d_out, int out_size, void* d_ws, size_t ws_size,
                              hipStream_t stream) {
  const float* x      = (const float*)d_in[0];
  const int*   packed = (const int*)d_in[1];
  const float* absmax = (const float*)d_in[2];
  const float* bias   = (const float*)d_in[3];
  float* out = (float*)d_out;

  unsigned short* xf = (unsigned short*)d_ws;                  // 1 MB
  float* parts = (float*)((char*)d_ws + (1 << 20));            // NC * 2 MB fp32

  qlin_prep<<<(M_ROWS * IN_K / 8 + 255) / 256, 256, 0, stream>>>(x, xf);

  const size_t need8 = (size_t)(1 << 20)
                     + (size_t)8 * M_ROWS * OUT_N * sizeof(float);
  if (ws_size >= need8) {
    qlin_main<8><<<(OUT_N / 64) * 8, 256, 0, stream>>>(packed, absmax, xf, parts);
    qlin_reduce<8><<<(M_ROWS * OUT_N / 4 + 255) / 256, 256, 0, stream>>>(parts, bias, out);
  } else {
    qlin_main<4><<<(OUT_N / 64) * 4, 256, 0, stream>>>(packed, absmax, xf, parts);
    qlin_reduce<4><<<(M_ROWS * OUT_N / 4 + 255) / 256, 256, 0, stream>>>(parts, bias, out);
  }
}